// Round 9
// baseline (168.881 us; speedup 1.0000x reference)
//
#include <hip/hip_runtime.h>
#include <math.h>

#define BB 32
#define SS 2048
#define EE 6144
#define KS1 8    // K-split gemm1 (K=2048, 256 k per block)
#define KS2 24   // K-split gemm2 (K=6144, 256 k per block)

typedef __bf16 bf16x8 __attribute__((ext_vector_type(8)));
typedef float f32x16 __attribute__((ext_vector_type(16)));
typedef float f32x4 __attribute__((ext_vector_type(4)));

__device__ __forceinline__ f32x4 ntload4(const float* p) {
  return __builtin_nontemporal_load((const f32x4*)p);
}

// ---------------- fused LN + attention (head_dim=1) + residual ----------------
// grid (SS/128, BB); block 256 = 4 waves. xout = attn(LN(xin)) + xin.
// If stats != nullptr, block x==0 also emits mean/var(ddof=1) of xin rows.
__global__ __launch_bounds__(256) void k_attn(const float* __restrict__ xin,
                                              float* __restrict__ xout,
                                              const float* __restrict__ g,
                                              const float* __restrict__ be,
                                              const float* __restrict__ ipw,
                                              const float* __restrict__ ipb,
                                              const float* __restrict__ owp,
                                              const float* __restrict__ obp,
                                              float* __restrict__ stats) {
  int b = blockIdx.y;
  const float* xrow = xin + b * SS;
  __shared__ float2 uv[SS];           // (u_j, v_j)  16 KB
  __shared__ float red[16];
  __shared__ float smu, srs, sk1, sk2;
  __shared__ float sp[2][3][2][64];   // [s|t][wave-1][m][il]  3 KB
  int tid = threadIdx.x;
  int lane = tid & 63, wid = tid >> 6;

  // phase 1: LN row stats
  float s = 0.f, s2 = 0.f;
  for (int j = tid; j < SS; j += 256) { float v = xrow[j]; s += v; s2 += v * v; }
  for (int off = 32; off; off >>= 1) { s += __shfl_down(s, off); s2 += __shfl_down(s2, off); }
  if (lane == 0) { red[wid] = s; red[4 + wid] = s2; }
  __syncthreads();
  if (tid == 0) {
    float ts = red[0] + red[1] + red[2] + red[3];
    float ts2 = red[4] + red[5] + red[6] + red[7];
    float mu = ts / SS;
    float var = ts2 / SS - mu * mu;
    smu = mu; srs = rsqrtf(var + 1e-5f);
    if (stats && blockIdx.x == 0) {
      stats[b] = mu;
      stats[BB + b] = (ts2 - SS * mu * mu) / (SS - 1);
    }
  }
  __syncthreads();
  float mu = smu, rs = srs;
  float wq = ipw[0], wk = ipw[1], wv = ipw[2];
  float bq = ipb[0], bk = ipb[1], bv = ipb[2];

  // phase 2: stage (u, v) into LDS + track u extremes (k is affine in u)
  float umax = -1e30f, umin = 1e30f;
  for (int j = tid; j < SS; j += 256) {
    float u = (xrow[j] - mu) * rs * g[j] + be[j];
    uv[j] = make_float2(u, fmaf(u, wv, bv));
    umax = fmaxf(umax, u);
    umin = fminf(umin, u);
  }
  for (int off = 32; off; off >>= 1) {
    umax = fmaxf(umax, __shfl_down(umax, off));
    umin = fminf(umin, __shfl_down(umin, off));
  }
  if (lane == 0) { red[8 + wid] = umax; red[12 + wid] = umin; }
  __syncthreads();
  if (tid == 0) {
    float ux = fmaxf(fmaxf(red[8], red[9]), fmaxf(red[10], red[11]));
    float un = fminf(fminf(red[12], red[13]), fminf(red[14], red[15]));
    sk1 = fmaf(ux, wk, bk);
    sk2 = fmaf(un, wk, bk);
  }
  __syncthreads();
  float k1 = sk1, k2 = sk2;

  // phase 3: softmax-weighted sum; arg = L2E*(q*wk)*u_j + L2E*(q*bk - m)
  const float L2E = 1.4426950408889634f;
  int i0 = blockIdx.x << 7;
  float q0 = fmaf(uv[i0 + lane].x, wq, bq);
  float q1 = fmaf(uv[i0 + 64 + lane].x, wq, bq);
  float m0 = fmaxf(q0 * k1, q0 * k2);
  float m1 = fmaxf(q1 * k1, q1 * k2);
  float a0 = L2E * q0 * wk, c0 = L2E * (q0 * bk - m0);
  float a1 = L2E * q1 * wk, c1 = L2E * (q1 * bk - m1);
  float s0 = 0.f, t0 = 0.f, s1 = 0.f, t1 = 0.f;
  int j0 = wid << 9;
#pragma unroll 4
  for (int j = j0; j < j0 + 512; j++) {
    float2 c = uv[j];
    float e0 = __builtin_amdgcn_exp2f(fmaf(a0, c.x, c0));
    float e1 = __builtin_amdgcn_exp2f(fmaf(a1, c.x, c1));
    s0 += e0; t0 = fmaf(e0, c.y, t0);
    s1 += e1; t1 = fmaf(e1, c.y, t1);
  }
  if (wid) {
    sp[0][wid - 1][0][lane] = s0; sp[0][wid - 1][1][lane] = s1;
    sp[1][wid - 1][0][lane] = t0; sp[1][wid - 1][1][lane] = t1;
  }
  __syncthreads();
  if (wid == 0) {
    s0 += sp[0][0][0][lane] + sp[0][1][0][lane] + sp[0][2][0][lane];
    t0 += sp[1][0][0][lane] + sp[1][1][0][lane] + sp[1][2][0][lane];
    s1 += sp[0][0][1][lane] + sp[0][1][1][lane] + sp[0][2][1][lane];
    t1 += sp[1][0][1][lane] + sp[1][1][1][lane] + sp[1][2][1][lane];
    float ow = owp[0], ob = obp[0];
    int i = i0 + lane;
    xout[b * SS + i] = fmaf(t0 / s0, ow, ob) + xrow[i];
    xout[b * SS + i + 64] = fmaf(t1 / s1, ow, ob) + xrow[i + 64];
  }
}

// ---------------- LayerNorm -> bf16 B-fragment layout Ubf[k/8][32][8] ----------------
__global__ __launch_bounds__(256) void k_ln_bf(const float* __restrict__ x,
                                               const float* __restrict__ g,
                                               const float* __restrict__ be,
                                               __bf16* __restrict__ ubf) {
  int b = blockIdx.x;
  const float* row = x + b * SS;
  float s = 0.f, s2 = 0.f;
  for (int j = threadIdx.x; j < SS; j += 256) { float v = row[j]; s += v; s2 += v * v; }
  __shared__ float sm[8];
  __shared__ float smu, srs;
  for (int off = 32; off; off >>= 1) { s += __shfl_down(s, off); s2 += __shfl_down(s2, off); }
  int lane = threadIdx.x & 63, wid = threadIdx.x >> 6;
  if (lane == 0) { sm[wid] = s; sm[4 + wid] = s2; }
  __syncthreads();
  if (threadIdx.x == 0) {
    float ts = sm[0] + sm[1] + sm[2] + sm[3];
    float ts2 = sm[4] + sm[5] + sm[6] + sm[7];
    float mu = ts / SS;
    float var = ts2 / SS - mu * mu;
    smu = mu;
    srs = rsqrtf(var + 1e-5f);
  }
  __syncthreads();
  float mu = smu, rs = srs;
  int t = threadIdx.x;
  float4 v0 = *reinterpret_cast<const float4*>(row + t * 8);
  float4 v1 = *reinterpret_cast<const float4*>(row + t * 8 + 4);
  float4 g0 = *reinterpret_cast<const float4*>(g + t * 8);
  float4 g1 = *reinterpret_cast<const float4*>(g + t * 8 + 4);
  float4 b0 = *reinterpret_cast<const float4*>(be + t * 8);
  float4 b1 = *reinterpret_cast<const float4*>(be + t * 8 + 4);
  bf16x8 o;
  o[0] = (__bf16)((v0.x - mu) * rs * g0.x + b0.x);
  o[1] = (__bf16)((v0.y - mu) * rs * g0.y + b0.y);
  o[2] = (__bf16)((v0.z - mu) * rs * g0.z + b0.z);
  o[3] = (__bf16)((v0.w - mu) * rs * g0.w + b0.w);
  o[4] = (__bf16)((v1.x - mu) * rs * g1.x + b1.x);
  o[5] = (__bf16)((v1.y - mu) * rs * g1.y + b1.y);
  o[6] = (__bf16)((v1.z - mu) * rs * g1.z + b1.z);
  o[7] = (__bf16)((v1.w - mu) * rs * g1.w + b1.w);
  *reinterpret_cast<bf16x8*>(ubf + t * 256 + b * 8) = o;
}

// ---------------- streaming MFMA GEMM with in-block k-pair reduce ----------------
// grid: (N/64, K/256); block 256 = 4 waves.
// wave w: rgrp = w&1 (rows e0+32*rgrp..+31), khalf = w>>1 (k in [kc+128*kh, +128)).
// khalf=1 waves dump acc to LDS; khalf=0 waves add and store one part slab per block.
__global__ __launch_bounds__(256) void k_gemm_mfma(const __bf16* __restrict__ Ubf,
                                                   const float* __restrict__ W,
                                                   float* __restrict__ part,
                                                   int K, int N) {
  __shared__ float ls[2][16][64];  // 8 KB, [rgrp][r][lane]: conflict-free
  int tid = threadIdx.x;
  int w = tid >> 6, lane = tid & 63;
  int l31 = lane & 31, h = lane >> 5;
  int rgrp = w & 1, kh = w >> 1;
  int e0 = (blockIdx.x << 6) + (rgrp << 5);
  int kc = (blockIdx.y << 8) + (kh << 7);
  const float* wp = W + (size_t)(e0 + l31) * K + kc + (h << 3);
  const __bf16* up = Ubf + (size_t)((kc >> 3) + h) * 256 + (l31 << 3);
  f32x16 acc = {0.f, 0.f, 0.f, 0.f, 0.f, 0.f, 0.f, 0.f,
                0.f, 0.f, 0.f, 0.f, 0.f, 0.f, 0.f, 0.f};
#pragma unroll
  for (int t = 0; t < 8; ++t) {
    f32x4 a0 = ntload4(wp + (t << 4));
    f32x4 a1 = ntload4(wp + (t << 4) + 4);
    bf16x8 bv = *reinterpret_cast<const bf16x8*>(up + (t << 9));
    bf16x8 av;
    av[0] = (__bf16)a0[0]; av[1] = (__bf16)a0[1]; av[2] = (__bf16)a0[2]; av[3] = (__bf16)a0[3];
    av[4] = (__bf16)a1[0]; av[5] = (__bf16)a1[1]; av[6] = (__bf16)a1[2]; av[7] = (__bf16)a1[3];
    acc = __builtin_amdgcn_mfma_f32_32x32x16_bf16(av, bv, acc, 0, 0, 0);
  }
  if (kh == 1) {
#pragma unroll
    for (int r = 0; r < 16; ++r) ls[rgrp][r][lane] = acc[r];
  }
  __syncthreads();
  if (kh == 0) {
    float* out = part + (size_t)blockIdx.y * ((size_t)N * 32);
#pragma unroll
    for (int r = 0; r < 16; ++r) {
      int e = e0 + (r & 3) + ((r >> 2) << 3) + (h << 2);
      __builtin_nontemporal_store(acc[r] + ls[rgrp][r][lane], out + (size_t)e * 32 + l31);
    }
  }
}

// ---------------- reduce gemm1 partials (KS1=8): bias + leakyrelu -> hbf ----------------
__global__ __launch_bounds__(256) void k_reduce1(const float* __restrict__ part,
                                                 const float* __restrict__ b1,
                                                 __bf16* __restrict__ hbf) {
  __shared__ float ls[256];
  int t = threadIdx.x;
  int base = blockIdx.x << 8;
  float v[8];
#pragma unroll
  for (int j = 0; j < 8; j++) v[j] = __builtin_nontemporal_load(part + (size_t)j * (EE * 32) + base + t);
  float s = 0.f;
#pragma unroll
  for (int j = 0; j < 8; j++) s += v[j];
  int e = (blockIdx.x << 3) + (t >> 5);
  s += b1[e];
  s = s >= 0.f ? s : 0.5f * s;
  ls[((t & 31) << 3) | (t >> 5)] = s;
  __syncthreads();
  hbf[base + t] = (__bf16)ls[t];
}

// ---------------- reduce gemm2 partials (KS2=24): bias + residual -> xbuf ----------------
__global__ __launch_bounds__(256) void k_reduce2(const float* __restrict__ part,
                                                 const float* __restrict__ b2,
                                                 float* __restrict__ xbuf) {
  __shared__ float ls[32][9];
  int t = threadIdx.x;
  int base = blockIdx.x << 8;
  float s = 0.f;
#pragma unroll
  for (int g = 0; g < KS2; g += 8) {
    float v[8];
#pragma unroll
    for (int j = 0; j < 8; j++) v[j] = __builtin_nontemporal_load(part + (size_t)(g + j) * (SS * 32) + base + t);
#pragma unroll
    for (int j = 0; j < 8; j++) s += v[j];
  }
  ls[t & 31][t >> 5] = s;
  __syncthreads();
  int r = t >> 3, sc = t & 7;
  int scol = (blockIdx.x << 3) + sc;
  xbuf[(size_t)r * SS + scol] += ls[r][sc] + b2[scol];
}

// ---------------- final renorm to original mean/var ----------------
__global__ __launch_bounds__(256) void k_final(const float* __restrict__ xbuf,
                                               const float* __restrict__ stats,
                                               float* __restrict__ out) {
  int b = blockIdx.x;
  const float* row = xbuf + b * SS;
  float s = 0.f, s2 = 0.f;
  for (int j = threadIdx.x; j < SS; j += 256) { float v = row[j]; s += v; s2 += v * v; }
  __shared__ float sm[8];
  __shared__ float smu, srs;
  for (int off = 32; off; off >>= 1) { s += __shfl_down(s, off); s2 += __shfl_down(s2, off); }
  int lane = threadIdx.x & 63, wid = threadIdx.x >> 6;
  if (lane == 0) { sm[wid] = s; sm[4 + wid] = s2; }
  __syncthreads();
  if (threadIdx.x == 0) {
    float ts = sm[0] + sm[1] + sm[2] + sm[3];
    float ts2 = sm[4] + sm[5] + sm[6] + sm[7];
    float mu = ts / SS;
    float var = (ts2 - SS * mu * mu) / (SS - 1);
    smu = mu;
    srs = rsqrtf(var + 2.220446049250313e-16f);
  }
  __syncthreads();
  float mu = smu, rs = srs;
  float scale = sqrtf(stats[BB + b] + 2.220446049250313e-16f);
  float mean0 = stats[b];
  for (int j = threadIdx.x; j < SS; j += 256) {
    out[b * SS + j] = (row[j] - mu) * rs * scale + mean0;
  }
}

extern "C" void kernel_launch(void* const* d_in, const int* in_sizes, int n_in,
                              void* d_out, int out_size, void* d_ws, size_t ws_size,
                              hipStream_t stream) {
  const float* x         = (const float*)d_in[0];
  const float* attn_ln_g = (const float*)d_in[1];
  const float* attn_ln_b = (const float*)d_in[2];
  const float* ipw       = (const float*)d_in[3];
  const float* ipb       = (const float*)d_in[4];
  const float* out_w     = (const float*)d_in[5];
  const float* out_b     = (const float*)d_in[6];
  const float* mlp_ln_g  = (const float*)d_in[7];
  const float* mlp_ln_b  = (const float*)d_in[8];
  const float* W1        = (const float*)d_in[9];
  const float* b1        = (const float*)d_in[10];
  const float* W2        = (const float*)d_in[11];
  const float* b2        = (const float*)d_in[12];

  float* ws    = (float*)d_ws;
  float* xA    = ws;                              // 65536 f (layer-1 output)
  float* xB    = xA + BB * SS;                    // 65536 f (layer-0 output)
  __bf16* ubf  = (__bf16*)(xB + BB * SS);         // 65536 bf16 (32768 f)
  __bf16* hbf  = (__bf16*)(xB + BB * SS + 32768); // 196608 bf16 (98304 f)
  float* part  = xB + BB * SS + 32768 + 98304;    // 1572864 f (6.3 MB)
  float* stats = part + (size_t)KS1 * EE * 32;    // 64 f

  for (int l = 0; l < 2; l++) {
    const float* xin = (l == 0) ? x : xB;
    float* xout      = (l == 0) ? xB : xA;
    // ---- attention block (LN fused; layer 0 also emits input stats) ----
    k_attn<<<dim3(SS / 128, BB), 256, 0, stream>>>(xin, xout,
                                                   attn_ln_g + l * SS, attn_ln_b + l * SS,
                                                   ipw + l * 3, ipb + l * 3,
                                                   out_w + l, out_b + l,
                                                   l == 0 ? stats : nullptr);
    // ---- MLP block ----
    k_ln_bf<<<BB, 256, 0, stream>>>(xout, mlp_ln_g + l * SS, mlp_ln_b + l * SS, ubf);
    k_gemm_mfma<<<dim3(EE / 64, KS1), 256, 0, stream>>>(ubf, W1 + (size_t)l * EE * SS,
                                                        part, SS, EE);
    k_reduce1<<<EE / 8, 256, 0, stream>>>(part, b1 + (size_t)l * EE, hbf);
    k_gemm_mfma<<<dim3(SS / 64, KS2), 256, 0, stream>>>(hbf, W2 + (size_t)l * SS * EE,
                                                        part, EE, SS);
    k_reduce2<<<SS / 8, 256, 0, stream>>>(part, b2 + (size_t)l * SS, xout);
  }

  k_final<<<BB, 256, 0, stream>>>(xA, stats, (float*)d_out);
}

// Round 10
// 136.029 us; speedup vs baseline: 1.2415x; 1.2415x over previous
//
#include <hip/hip_runtime.h>
#include <math.h>

#define BB 32
#define SS 2048
#define EE 6144
#define KS1 8    // K-split gemm1 (K=2048, 256 k per block)
#define KS2 24   // K-split gemm2 (K=6144, 256 k per block)

typedef __bf16 bf16x8 __attribute__((ext_vector_type(8)));
typedef float f32x16 __attribute__((ext_vector_type(16)));

// ---------------- fused LN + attention (head_dim=1) + residual ----------------
// grid (SS/128, BB); block 256 = 4 waves. xout = attn(LN(xin)) + xin.
// If stats != nullptr, block x==0 also emits mean/var(ddof=1) of xin rows.
__global__ __launch_bounds__(256) void k_attn(const float* __restrict__ xin,
                                              float* __restrict__ xout,
                                              const float* __restrict__ g,
                                              const float* __restrict__ be,
                                              const float* __restrict__ ipw,
                                              const float* __restrict__ ipb,
                                              const float* __restrict__ owp,
                                              const float* __restrict__ obp,
                                              float* __restrict__ stats) {
  int b = blockIdx.y;
  const float* xrow = xin + b * SS;
  __shared__ float2 uv[SS];           // (u_j, v_j)  16 KB
  __shared__ float red[16];
  __shared__ float smu, srs, sk1, sk2;
  __shared__ float sp[2][3][2][64];   // [s|t][wave-1][m][il]  3 KB
  int tid = threadIdx.x;
  int lane = tid & 63, wid = tid >> 6;

  // phase 1: LN row stats
  float s = 0.f, s2 = 0.f;
  for (int j = tid; j < SS; j += 256) { float v = xrow[j]; s += v; s2 += v * v; }
  for (int off = 32; off; off >>= 1) { s += __shfl_down(s, off); s2 += __shfl_down(s2, off); }
  if (lane == 0) { red[wid] = s; red[4 + wid] = s2; }
  __syncthreads();
  if (tid == 0) {
    float ts = red[0] + red[1] + red[2] + red[3];
    float ts2 = red[4] + red[5] + red[6] + red[7];
    float mu = ts / SS;
    float var = ts2 / SS - mu * mu;
    smu = mu; srs = rsqrtf(var + 1e-5f);
    if (stats && blockIdx.x == 0) {
      stats[b] = mu;
      stats[BB + b] = (ts2 - SS * mu * mu) / (SS - 1);
    }
  }
  __syncthreads();
  float mu = smu, rs = srs;
  float wq = ipw[0], wk = ipw[1], wv = ipw[2];
  float bq = ipb[0], bk = ipb[1], bv = ipb[2];

  // phase 2: stage (u, v) into LDS + track u extremes (k is affine in u)
  float umax = -1e30f, umin = 1e30f;
  for (int j = tid; j < SS; j += 256) {
    float u = (xrow[j] - mu) * rs * g[j] + be[j];
    uv[j] = make_float2(u, fmaf(u, wv, bv));
    umax = fmaxf(umax, u);
    umin = fminf(umin, u);
  }
  for (int off = 32; off; off >>= 1) {
    umax = fmaxf(umax, __shfl_down(umax, off));
    umin = fminf(umin, __shfl_down(umin, off));
  }
  if (lane == 0) { red[8 + wid] = umax; red[12 + wid] = umin; }
  __syncthreads();
  if (tid == 0) {
    float ux = fmaxf(fmaxf(red[8], red[9]), fmaxf(red[10], red[11]));
    float un = fminf(fminf(red[12], red[13]), fminf(red[14], red[15]));
    sk1 = fmaf(ux, wk, bk);
    sk2 = fmaf(un, wk, bk);
  }
  __syncthreads();
  float k1 = sk1, k2 = sk2;

  // phase 3: softmax-weighted sum; arg = L2E*(q*wk)*u_j + L2E*(q*bk - m)
  const float L2E = 1.4426950408889634f;
  int i0 = blockIdx.x << 7;
  float q0 = fmaf(uv[i0 + lane].x, wq, bq);
  float q1 = fmaf(uv[i0 + 64 + lane].x, wq, bq);
  float m0 = fmaxf(q0 * k1, q0 * k2);
  float m1 = fmaxf(q1 * k1, q1 * k2);
  float a0 = L2E * q0 * wk, c0 = L2E * (q0 * bk - m0);
  float a1 = L2E * q1 * wk, c1 = L2E * (q1 * bk - m1);
  float s0 = 0.f, t0 = 0.f, s1 = 0.f, t1 = 0.f;
  int j0 = wid << 9;
#pragma unroll 4
  for (int j = j0; j < j0 + 512; j++) {
    float2 c = uv[j];
    float e0 = __builtin_amdgcn_exp2f(fmaf(a0, c.x, c0));
    float e1 = __builtin_amdgcn_exp2f(fmaf(a1, c.x, c1));
    s0 += e0; t0 = fmaf(e0, c.y, t0);
    s1 += e1; t1 = fmaf(e1, c.y, t1);
  }
  if (wid) {
    sp[0][wid - 1][0][lane] = s0; sp[0][wid - 1][1][lane] = s1;
    sp[1][wid - 1][0][lane] = t0; sp[1][wid - 1][1][lane] = t1;
  }
  __syncthreads();
  if (wid == 0) {
    s0 += sp[0][0][0][lane] + sp[0][1][0][lane] + sp[0][2][0][lane];
    t0 += sp[1][0][0][lane] + sp[1][1][0][lane] + sp[1][2][0][lane];
    s1 += sp[0][0][1][lane] + sp[0][1][1][lane] + sp[0][2][1][lane];
    t1 += sp[1][0][1][lane] + sp[1][1][1][lane] + sp[1][2][1][lane];
    float ow = owp[0], ob = obp[0];
    int i = i0 + lane;
    xout[b * SS + i] = fmaf(t0 / s0, ow, ob) + xrow[i];
    xout[b * SS + i + 64] = fmaf(t1 / s1, ow, ob) + xrow[i + 64];
  }
}

// ---------------- LayerNorm -> bf16 B-fragment layout Ubf[k/8][32][8] ----------------
__global__ __launch_bounds__(256) void k_ln_bf(const float* __restrict__ x,
                                               const float* __restrict__ g,
                                               const float* __restrict__ be,
                                               __bf16* __restrict__ ubf) {
  int b = blockIdx.x;
  const float* row = x + b * SS;
  float s = 0.f, s2 = 0.f;
  for (int j = threadIdx.x; j < SS; j += 256) { float v = row[j]; s += v; s2 += v * v; }
  __shared__ float sm[8];
  __shared__ float smu, srs;
  for (int off = 32; off; off >>= 1) { s += __shfl_down(s, off); s2 += __shfl_down(s2, off); }
  int lane = threadIdx.x & 63, wid = threadIdx.x >> 6;
  if (lane == 0) { sm[wid] = s; sm[4 + wid] = s2; }
  __syncthreads();
  if (threadIdx.x == 0) {
    float ts = sm[0] + sm[1] + sm[2] + sm[3];
    float ts2 = sm[4] + sm[5] + sm[6] + sm[7];
    float mu = ts / SS;
    float var = ts2 / SS - mu * mu;
    smu = mu;
    srs = rsqrtf(var + 1e-5f);
  }
  __syncthreads();
  float mu = smu, rs = srs;
  int t = threadIdx.x;
  float4 v0 = *reinterpret_cast<const float4*>(row + t * 8);
  float4 v1 = *reinterpret_cast<const float4*>(row + t * 8 + 4);
  float4 g0 = *reinterpret_cast<const float4*>(g + t * 8);
  float4 g1 = *reinterpret_cast<const float4*>(g + t * 8 + 4);
  float4 b0 = *reinterpret_cast<const float4*>(be + t * 8);
  float4 b1 = *reinterpret_cast<const float4*>(be + t * 8 + 4);
  bf16x8 o;
  o[0] = (__bf16)((v0.x - mu) * rs * g0.x + b0.x);
  o[1] = (__bf16)((v0.y - mu) * rs * g0.y + b0.y);
  o[2] = (__bf16)((v0.z - mu) * rs * g0.z + b0.z);
  o[3] = (__bf16)((v0.w - mu) * rs * g0.w + b0.w);
  o[4] = (__bf16)((v1.x - mu) * rs * g1.x + b1.x);
  o[5] = (__bf16)((v1.y - mu) * rs * g1.y + b1.y);
  o[6] = (__bf16)((v1.z - mu) * rs * g1.z + b1.z);
  o[7] = (__bf16)((v1.w - mu) * rs * g1.w + b1.w);
  *reinterpret_cast<bf16x8*>(ubf + t * 256 + b * 8) = o;
}

// ---------------- streaming MFMA GEMM with in-block k-pair reduce ----------------
// grid: (N/64, K/256); block 256 = 4 waves.
// wave w: rgrp = w&1 (rows e0+32*rgrp..+31), khalf = w>>1 (k in [kc+128*kh, +128)).
// khalf=1 waves dump acc to LDS; khalf=0 waves add and store one part slab per block.
__global__ __launch_bounds__(256) void k_gemm_mfma(const __bf16* __restrict__ Ubf,
                                                   const float* __restrict__ W,
                                                   float* __restrict__ part,
                                                   int K, int N) {
  __shared__ float ls[2][16][64];  // 8 KB, [rgrp][r][lane]: conflict-free
  int tid = threadIdx.x;
  int w = tid >> 6, lane = tid & 63;
  int l31 = lane & 31, h = lane >> 5;
  int rgrp = w & 1, kh = w >> 1;
  int e0 = (blockIdx.x << 6) + (rgrp << 5);
  int kc = (blockIdx.y << 8) + (kh << 7);
  const float* wp = W + (size_t)(e0 + l31) * K + kc + (h << 3);
  const __bf16* up = Ubf + (size_t)((kc >> 3) + h) * 256 + (l31 << 3);
  f32x16 acc = {0.f, 0.f, 0.f, 0.f, 0.f, 0.f, 0.f, 0.f,
                0.f, 0.f, 0.f, 0.f, 0.f, 0.f, 0.f, 0.f};
#pragma unroll
  for (int t = 0; t < 8; ++t) {
    float4 a0 = *reinterpret_cast<const float4*>(wp + (t << 4));
    float4 a1 = *reinterpret_cast<const float4*>(wp + (t << 4) + 4);
    bf16x8 bv = *reinterpret_cast<const bf16x8*>(up + (t << 9));
    bf16x8 av;
    av[0] = (__bf16)a0.x; av[1] = (__bf16)a0.y; av[2] = (__bf16)a0.z; av[3] = (__bf16)a0.w;
    av[4] = (__bf16)a1.x; av[5] = (__bf16)a1.y; av[6] = (__bf16)a1.z; av[7] = (__bf16)a1.w;
    acc = __builtin_amdgcn_mfma_f32_32x32x16_bf16(av, bv, acc, 0, 0, 0);
  }
  if (kh == 1) {
#pragma unroll
    for (int r = 0; r < 16; ++r) ls[rgrp][r][lane] = acc[r];
  }
  __syncthreads();
  if (kh == 0) {
    float* out = part + (size_t)blockIdx.y * ((size_t)N * 32);
#pragma unroll
    for (int r = 0; r < 16; ++r) {
      int e = e0 + (r & 3) + ((r >> 2) << 3) + (h << 2);
      out[(size_t)e * 32 + l31] = acc[r] + ls[rgrp][r][lane];
    }
  }
}

// ---------------- reduce gemm1 partials (KS1=8): bias + leakyrelu -> hbf ----------------
__global__ __launch_bounds__(256) void k_reduce1(const float* __restrict__ part,
                                                 const float* __restrict__ b1,
                                                 __bf16* __restrict__ hbf) {
  __shared__ float ls[256];
  int t = threadIdx.x;
  int base = blockIdx.x << 8;
  float v[8];
#pragma unroll
  for (int j = 0; j < 8; j++) v[j] = part[(size_t)j * (EE * 32) + base + t];
  float s = 0.f;
#pragma unroll
  for (int j = 0; j < 8; j++) s += v[j];
  int e = (blockIdx.x << 3) + (t >> 5);
  s += b1[e];
  s = s >= 0.f ? s : 0.5f * s;
  ls[((t & 31) << 3) | (t >> 5)] = s;
  __syncthreads();
  hbf[base + t] = (__bf16)ls[t];
}

// ---------------- reduce gemm2 partials (KS2=24): bias + residual -> xbuf ----------------
__global__ __launch_bounds__(256) void k_reduce2(const float* __restrict__ part,
                                                 const float* __restrict__ b2,
                                                 float* __restrict__ xbuf) {
  __shared__ float ls[32][9];
  int t = threadIdx.x;
  int base = blockIdx.x << 8;
  float s = 0.f;
#pragma unroll
  for (int g = 0; g < KS2; g += 8) {
    float v[8];
#pragma unroll
    for (int j = 0; j < 8; j++) v[j] = part[(size_t)(g + j) * (SS * 32) + base + t];
#pragma unroll
    for (int j = 0; j < 8; j++) s += v[j];
  }
  ls[t & 31][t >> 5] = s;
  __syncthreads();
  int r = t >> 3, sc = t & 7;
  int scol = (blockIdx.x << 3) + sc;
  xbuf[(size_t)r * SS + scol] += ls[r][sc] + b2[scol];
}

// ---------------- final renorm to original mean/var ----------------
__global__ __launch_bounds__(256) void k_final(const float* __restrict__ xbuf,
                                               const float* __restrict__ stats,
                                               float* __restrict__ out) {
  int b = blockIdx.x;
  const float* row = xbuf + b * SS;
  float s = 0.f, s2 = 0.f;
  for (int j = threadIdx.x; j < SS; j += 256) { float v = row[j]; s += v; s2 += v * v; }
  __shared__ float sm[8];
  __shared__ float smu, srs;
  for (int off = 32; off; off >>= 1) { s += __shfl_down(s, off); s2 += __shfl_down(s2, off); }
  int lane = threadIdx.x & 63, wid = threadIdx.x >> 6;
  if (lane == 0) { sm[wid] = s; sm[4 + wid] = s2; }
  __syncthreads();
  if (threadIdx.x == 0) {
    float ts = sm[0] + sm[1] + sm[2] + sm[3];
    float ts2 = sm[4] + sm[5] + sm[6] + sm[7];
    float mu = ts / SS;
    float var = (ts2 - SS * mu * mu) / (SS - 1);
    smu = mu;
    srs = rsqrtf(var + 2.220446049250313e-16f);
  }
  __syncthreads();
  float mu = smu, rs = srs;
  float scale = sqrtf(stats[BB + b] + 2.220446049250313e-16f);
  float mean0 = stats[b];
  for (int j = threadIdx.x; j < SS; j += 256) {
    out[b * SS + j] = (row[j] - mu) * rs * scale + mean0;
  }
}

extern "C" void kernel_launch(void* const* d_in, const int* in_sizes, int n_in,
                              void* d_out, int out_size, void* d_ws, size_t ws_size,
                              hipStream_t stream) {
  const float* x         = (const float*)d_in[0];
  const float* attn_ln_g = (const float*)d_in[1];
  const float* attn_ln_b = (const float*)d_in[2];
  const float* ipw       = (const float*)d_in[3];
  const float* ipb       = (const float*)d_in[4];
  const float* out_w     = (const float*)d_in[5];
  const float* out_b     = (const float*)d_in[6];
  const float* mlp_ln_g  = (const float*)d_in[7];
  const float* mlp_ln_b  = (const float*)d_in[8];
  const float* W1        = (const float*)d_in[9];
  const float* b1        = (const float*)d_in[10];
  const float* W2        = (const float*)d_in[11];
  const float* b2        = (const float*)d_in[12];

  float* ws    = (float*)d_ws;
  float* xA    = ws;                              // 65536 f (layer-1 output)
  float* xB    = xA + BB * SS;                    // 65536 f (layer-0 output)
  __bf16* ubf  = (__bf16*)(xB + BB * SS);         // 65536 bf16 (32768 f)
  __bf16* hbf  = (__bf16*)(xB + BB * SS + 32768); // 196608 bf16 (98304 f)
  float* part  = xB + BB * SS + 32768 + 98304;    // 1572864 f (6.3 MB)
  float* stats = part + (size_t)KS1 * EE * 32;    // 64 f

  for (int l = 0; l < 2; l++) {
    const float* xin = (l == 0) ? x : xB;
    float* xout      = (l == 0) ? xB : xA;
    // ---- attention block (LN fused; layer 0 also emits input stats) ----
    k_attn<<<dim3(SS / 128, BB), 256, 0, stream>>>(xin, xout,
                                                   attn_ln_g + l * SS, attn_ln_b + l * SS,
                                                   ipw + l * 3, ipb + l * 3,
                                                   out_w + l, out_b + l,
                                                   l == 0 ? stats : nullptr);
    // ---- MLP block ----
    k_ln_bf<<<BB, 256, 0, stream>>>(xout, mlp_ln_g + l * SS, mlp_ln_b + l * SS, ubf);
    k_gemm_mfma<<<dim3(EE / 64, KS1), 256, 0, stream>>>(ubf, W1 + (size_t)l * EE * SS,
                                                        part, SS, EE);
    k_reduce1<<<EE / 8, 256, 0, stream>>>(part, b1 + (size_t)l * EE, hbf);
    k_gemm_mfma<<<dim3(SS / 64, KS2), 256, 0, stream>>>(hbf, W2 + (size_t)l * SS * EE,
                                                        part, EE, SS);
    k_reduce2<<<SS / 8, 256, 0, stream>>>(part, b2 + (size_t)l * SS, xout);
  }

  k_final<<<BB, 256, 0, stream>>>(xA, stats, (float*)d_out);
}

// Round 11
// 130.277 us; speedup vs baseline: 1.2963x; 1.0441x over previous
//
#include <hip/hip_runtime.h>
#include <math.h>

#define BB 32
#define SS 2048
#define EE 6144
#define KS1 8    // K-split gemm1 (K=2048, 256 k per block)
#define KS2 24   // K-split gemm2 (K=6144, 256 k per block)

typedef __bf16 bf16x8 __attribute__((ext_vector_type(8)));
typedef float f32x16 __attribute__((ext_vector_type(16)));
typedef float f32x4 __attribute__((ext_vector_type(4)));

// ---------------- fused LN + attention (head_dim=1) + residual ----------------
// grid (SS/128, BB); block 256 = 4 waves. xout = attn(LN(xin)) + xin.
// If stats != nullptr, block x==0 also emits mean/var(ddof=1) of xin rows.
__global__ __launch_bounds__(256) void k_attn(const float* __restrict__ xin,
                                              float* __restrict__ xout,
                                              const float* __restrict__ g,
                                              const float* __restrict__ be,
                                              const float* __restrict__ ipw,
                                              const float* __restrict__ ipb,
                                              const float* __restrict__ owp,
                                              const float* __restrict__ obp,
                                              float* __restrict__ stats) {
  int b = blockIdx.y;
  const float* xrow = xin + b * SS;
  __shared__ float2 uv[SS];           // (u_j, v_j)  16 KB
  __shared__ float red[16];
  __shared__ float smu, srs, sk1, sk2;
  __shared__ float sp[2][3][2][64];   // [s|t][wave-1][m][il]  3 KB
  int tid = threadIdx.x;
  int lane = tid & 63, wid = tid >> 6;

  // phase 1: LN row stats
  float s = 0.f, s2 = 0.f;
  for (int j = tid; j < SS; j += 256) { float v = xrow[j]; s += v; s2 += v * v; }
  for (int off = 32; off; off >>= 1) { s += __shfl_down(s, off); s2 += __shfl_down(s2, off); }
  if (lane == 0) { red[wid] = s; red[4 + wid] = s2; }
  __syncthreads();
  if (tid == 0) {
    float ts = red[0] + red[1] + red[2] + red[3];
    float ts2 = red[4] + red[5] + red[6] + red[7];
    float mu = ts / SS;
    float var = ts2 / SS - mu * mu;
    smu = mu; srs = rsqrtf(var + 1e-5f);
    if (stats && blockIdx.x == 0) {
      stats[b] = mu;
      stats[BB + b] = (ts2 - SS * mu * mu) / (SS - 1);
    }
  }
  __syncthreads();
  float mu = smu, rs = srs;
  float wq = ipw[0], wk = ipw[1], wv = ipw[2];
  float bq = ipb[0], bk = ipb[1], bv = ipb[2];

  // phase 2: stage (u, v) into LDS + track u extremes (k is affine in u)
  float umax = -1e30f, umin = 1e30f;
  for (int j = tid; j < SS; j += 256) {
    float u = (xrow[j] - mu) * rs * g[j] + be[j];
    uv[j] = make_float2(u, fmaf(u, wv, bv));
    umax = fmaxf(umax, u);
    umin = fminf(umin, u);
  }
  for (int off = 32; off; off >>= 1) {
    umax = fmaxf(umax, __shfl_down(umax, off));
    umin = fminf(umin, __shfl_down(umin, off));
  }
  if (lane == 0) { red[8 + wid] = umax; red[12 + wid] = umin; }
  __syncthreads();
  if (tid == 0) {
    float ux = fmaxf(fmaxf(red[8], red[9]), fmaxf(red[10], red[11]));
    float un = fminf(fminf(red[12], red[13]), fminf(red[14], red[15]));
    sk1 = fmaf(ux, wk, bk);
    sk2 = fmaf(un, wk, bk);
  }
  __syncthreads();
  float k1 = sk1, k2 = sk2;

  // phase 3: softmax-weighted sum; arg = L2E*(q*wk)*u_j + L2E*(q*bk - m)
  const float L2E = 1.4426950408889634f;
  int i0 = blockIdx.x << 7;
  float q0 = fmaf(uv[i0 + lane].x, wq, bq);
  float q1 = fmaf(uv[i0 + 64 + lane].x, wq, bq);
  float m0 = fmaxf(q0 * k1, q0 * k2);
  float m1 = fmaxf(q1 * k1, q1 * k2);
  float a0 = L2E * q0 * wk, c0 = L2E * (q0 * bk - m0);
  float a1 = L2E * q1 * wk, c1 = L2E * (q1 * bk - m1);
  float s0 = 0.f, t0 = 0.f, s1 = 0.f, t1 = 0.f;
  int j0 = wid << 9;
#pragma unroll 4
  for (int j = j0; j < j0 + 512; j++) {
    float2 c = uv[j];
    float e0 = __builtin_amdgcn_exp2f(fmaf(a0, c.x, c0));
    float e1 = __builtin_amdgcn_exp2f(fmaf(a1, c.x, c1));
    s0 += e0; t0 = fmaf(e0, c.y, t0);
    s1 += e1; t1 = fmaf(e1, c.y, t1);
  }
  if (wid) {
    sp[0][wid - 1][0][lane] = s0; sp[0][wid - 1][1][lane] = s1;
    sp[1][wid - 1][0][lane] = t0; sp[1][wid - 1][1][lane] = t1;
  }
  __syncthreads();
  if (wid == 0) {
    s0 += sp[0][0][0][lane] + sp[0][1][0][lane] + sp[0][2][0][lane];
    t0 += sp[1][0][0][lane] + sp[1][1][0][lane] + sp[1][2][0][lane];
    s1 += sp[0][0][1][lane] + sp[0][1][1][lane] + sp[0][2][1][lane];
    t1 += sp[1][0][1][lane] + sp[1][1][1][lane] + sp[1][2][1][lane];
    float ow = owp[0], ob = obp[0];
    int i = i0 + lane;
    xout[b * SS + i] = fmaf(t0 / s0, ow, ob) + xrow[i];
    xout[b * SS + i + 64] = fmaf(t1 / s1, ow, ob) + xrow[i + 64];
  }
}

// ---------------- LayerNorm -> bf16 B-fragment layout Ubf[k/8][32][8] ----------------
__global__ __launch_bounds__(256) void k_ln_bf(const float* __restrict__ x,
                                               const float* __restrict__ g,
                                               const float* __restrict__ be,
                                               __bf16* __restrict__ ubf) {
  int b = blockIdx.x;
  const float* row = x + b * SS;
  float s = 0.f, s2 = 0.f;
  for (int j = threadIdx.x; j < SS; j += 256) { float v = row[j]; s += v; s2 += v * v; }
  __shared__ float sm[8];
  __shared__ float smu, srs;
  for (int off = 32; off; off >>= 1) { s += __shfl_down(s, off); s2 += __shfl_down(s2, off); }
  int lane = threadIdx.x & 63, wid = threadIdx.x >> 6;
  if (lane == 0) { sm[wid] = s; sm[4 + wid] = s2; }
  __syncthreads();
  if (threadIdx.x == 0) {
    float ts = sm[0] + sm[1] + sm[2] + sm[3];
    float ts2 = sm[4] + sm[5] + sm[6] + sm[7];
    float mu = ts / SS;
    float var = ts2 / SS - mu * mu;
    smu = mu;
    srs = rsqrtf(var + 1e-5f);
  }
  __syncthreads();
  float mu = smu, rs = srs;
  int t = threadIdx.x;
  float4 v0 = *reinterpret_cast<const float4*>(row + t * 8);
  float4 v1 = *reinterpret_cast<const float4*>(row + t * 8 + 4);
  float4 g0 = *reinterpret_cast<const float4*>(g + t * 8);
  float4 g1 = *reinterpret_cast<const float4*>(g + t * 8 + 4);
  float4 b0 = *reinterpret_cast<const float4*>(be + t * 8);
  float4 b1 = *reinterpret_cast<const float4*>(be + t * 8 + 4);
  bf16x8 o;
  o[0] = (__bf16)((v0.x - mu) * rs * g0.x + b0.x);
  o[1] = (__bf16)((v0.y - mu) * rs * g0.y + b0.y);
  o[2] = (__bf16)((v0.z - mu) * rs * g0.z + b0.z);
  o[3] = (__bf16)((v0.w - mu) * rs * g0.w + b0.w);
  o[4] = (__bf16)((v1.x - mu) * rs * g1.x + b1.x);
  o[5] = (__bf16)((v1.y - mu) * rs * g1.y + b1.y);
  o[6] = (__bf16)((v1.z - mu) * rs * g1.z + b1.z);
  o[7] = (__bf16)((v1.w - mu) * rs * g1.w + b1.w);
  *reinterpret_cast<bf16x8*>(ubf + t * 256 + b * 8) = o;
}

// ---------------- streaming MFMA GEMM with in-block k-pair reduce ----------------
// grid: (N/64, K/256); block 256 = 4 waves.
// wave w: rgrp = w&1 (rows e0+32*rgrp..+31), khalf = w>>1 (k in [kc+128*kh, +128)).
// All 24 global loads (16x W f32x4 + 8x U bf16x8) issued upfront into register
// buffers (fully unrolled -> compile-time indices, no scratch) so the wave has
// ~24KB in flight before the first waitcnt; __launch_bounds__(256,2) relaxes
// the VGPR cap to let the compiler keep the whole buffer live.
__global__ __launch_bounds__(256, 2) void k_gemm_mfma(const __bf16* __restrict__ Ubf,
                                                      const float* __restrict__ W,
                                                      float* __restrict__ part,
                                                      int K, int N) {
  __shared__ float ls[2][16][64];  // 8 KB, [rgrp][r][lane]: conflict-free
  int tid = threadIdx.x;
  int w = tid >> 6, lane = tid & 63;
  int l31 = lane & 31, h = lane >> 5;
  int rgrp = w & 1, kh = w >> 1;
  int e0 = (blockIdx.x << 6) + (rgrp << 5);
  int kc = (blockIdx.y << 8) + (kh << 7);
  const float* wp = W + (size_t)(e0 + l31) * K + kc + (h << 3);
  const __bf16* up = Ubf + (size_t)((kc >> 3) + h) * 256 + (l31 << 3);

  f32x4 wb[16];
  bf16x8 ub[8];
#pragma unroll
  for (int t = 0; t < 8; ++t) {
    wb[2 * t]     = *reinterpret_cast<const f32x4*>(wp + (t << 4));
    wb[2 * t + 1] = *reinterpret_cast<const f32x4*>(wp + (t << 4) + 4);
    ub[t]         = *reinterpret_cast<const bf16x8*>(up + (t << 9));
  }

  f32x16 acc = {0.f, 0.f, 0.f, 0.f, 0.f, 0.f, 0.f, 0.f,
                0.f, 0.f, 0.f, 0.f, 0.f, 0.f, 0.f, 0.f};
#pragma unroll
  for (int t = 0; t < 8; ++t) {
    bf16x8 av;
    av[0] = (__bf16)wb[2 * t][0];     av[1] = (__bf16)wb[2 * t][1];
    av[2] = (__bf16)wb[2 * t][2];     av[3] = (__bf16)wb[2 * t][3];
    av[4] = (__bf16)wb[2 * t + 1][0]; av[5] = (__bf16)wb[2 * t + 1][1];
    av[6] = (__bf16)wb[2 * t + 1][2]; av[7] = (__bf16)wb[2 * t + 1][3];
    acc = __builtin_amdgcn_mfma_f32_32x32x16_bf16(av, ub[t], acc, 0, 0, 0);
  }

  if (kh == 1) {
#pragma unroll
    for (int r = 0; r < 16; ++r) ls[rgrp][r][lane] = acc[r];
  }
  __syncthreads();
  if (kh == 0) {
    float* out = part + (size_t)blockIdx.y * ((size_t)N * 32);
#pragma unroll
    for (int r = 0; r < 16; ++r) {
      int e = e0 + (r & 3) + ((r >> 2) << 3) + (h << 2);
      out[(size_t)e * 32 + l31] = acc[r] + ls[rgrp][r][lane];
    }
  }
}

// ---------------- reduce gemm1 partials (KS1=8): bias + leakyrelu -> hbf ----------------
__global__ __launch_bounds__(256) void k_reduce1(const float* __restrict__ part,
                                                 const float* __restrict__ b1,
                                                 __bf16* __restrict__ hbf) {
  __shared__ float ls[256];
  int t = threadIdx.x;
  int base = blockIdx.x << 8;
  float v[8];
#pragma unroll
  for (int j = 0; j < 8; j++) v[j] = part[(size_t)j * (EE * 32) + base + t];
  float s = 0.f;
#pragma unroll
  for (int j = 0; j < 8; j++) s += v[j];
  int e = (blockIdx.x << 3) + (t >> 5);
  s += b1[e];
  s = s >= 0.f ? s : 0.5f * s;
  ls[((t & 31) << 3) | (t >> 5)] = s;
  __syncthreads();
  hbf[base + t] = (__bf16)ls[t];
}

// ---------------- reduce gemm2 partials (KS2=24): bias + residual -> xbuf ----------------
__global__ __launch_bounds__(256) void k_reduce2(const float* __restrict__ part,
                                                 const float* __restrict__ b2,
                                                 float* __restrict__ xbuf) {
  __shared__ float ls[32][9];
  int t = threadIdx.x;
  int base = blockIdx.x << 8;
  float s = 0.f;
#pragma unroll
  for (int g = 0; g < KS2; g += 8) {
    float v[8];
#pragma unroll
    for (int j = 0; j < 8; j++) v[j] = part[(size_t)(g + j) * (SS * 32) + base + t];
#pragma unroll
    for (int j = 0; j < 8; j++) s += v[j];
  }
  ls[t & 31][t >> 5] = s;
  __syncthreads();
  int r = t >> 3, sc = t & 7;
  int scol = (blockIdx.x << 3) + sc;
  xbuf[(size_t)r * SS + scol] += ls[r][sc] + b2[scol];
}

// ---------------- final renorm to original mean/var ----------------
__global__ __launch_bounds__(256) void k_final(const float* __restrict__ xbuf,
                                               const float* __restrict__ stats,
                                               float* __restrict__ out) {
  int b = blockIdx.x;
  const float* row = xbuf + b * SS;
  float s = 0.f, s2 = 0.f;
  for (int j = threadIdx.x; j < SS; j += 256) { float v = row[j]; s += v; s2 += v * v; }
  __shared__ float sm[8];
  __shared__ float smu, srs;
  for (int off = 32; off; off >>= 1) { s += __shfl_down(s, off); s2 += __shfl_down(s2, off); }
  int lane = threadIdx.x & 63, wid = threadIdx.x >> 6;
  if (lane == 0) { sm[wid] = s; sm[4 + wid] = s2; }
  __syncthreads();
  if (threadIdx.x == 0) {
    float ts = sm[0] + sm[1] + sm[2] + sm[3];
    float ts2 = sm[4] + sm[5] + sm[6] + sm[7];
    float mu = ts / SS;
    float var = (ts2 - SS * mu * mu) / (SS - 1);
    smu = mu;
    srs = rsqrtf(var + 2.220446049250313e-16f);
  }
  __syncthreads();
  float mu = smu, rs = srs;
  float scale = sqrtf(stats[BB + b] + 2.220446049250313e-16f);
  float mean0 = stats[b];
  for (int j = threadIdx.x; j < SS; j += 256) {
    out[b * SS + j] = (row[j] - mu) * rs * scale + mean0;
  }
}

extern "C" void kernel_launch(void* const* d_in, const int* in_sizes, int n_in,
                              void* d_out, int out_size, void* d_ws, size_t ws_size,
                              hipStream_t stream) {
  const float* x         = (const float*)d_in[0];
  const float* attn_ln_g = (const float*)d_in[1];
  const float* attn_ln_b = (const float*)d_in[2];
  const float* ipw       = (const float*)d_in[3];
  const float* ipb       = (const float*)d_in[4];
  const float* out_w     = (const float*)d_in[5];
  const float* out_b     = (const float*)d_in[6];
  const float* mlp_ln_g  = (const float*)d_in[7];
  const float* mlp_ln_b  = (const float*)d_in[8];
  const float* W1        = (const float*)d_in[9];
  const float* b1        = (const float*)d_in[10];
  const float* W2        = (const float*)d_in[11];
  const float* b2        = (const float*)d_in[12];

  float* ws    = (float*)d_ws;
  float* xA    = ws;                              // 65536 f (layer-1 output)
  float* xB    = xA + BB * SS;                    // 65536 f (layer-0 output)
  __bf16* ubf  = (__bf16*)(xB + BB * SS);         // 65536 bf16 (32768 f)
  __bf16* hbf  = (__bf16*)(xB + BB * SS + 32768); // 196608 bf16 (98304 f)
  float* part  = xB + BB * SS + 32768 + 98304;    // 1572864 f (6.3 MB)
  float* stats = part + (size_t)KS1 * EE * 32;    // 64 f

  for (int l = 0; l < 2; l++) {
    const float* xin = (l == 0) ? x : xB;
    float* xout      = (l == 0) ? xB : xA;
    // ---- attention block (LN fused; layer 0 also emits input stats) ----
    k_attn<<<dim3(SS / 128, BB), 256, 0, stream>>>(xin, xout,
                                                   attn_ln_g + l * SS, attn_ln_b + l * SS,
                                                   ipw + l * 3, ipb + l * 3,
                                                   out_w + l, out_b + l,
                                                   l == 0 ? stats : nullptr);
    // ---- MLP block ----
    k_ln_bf<<<BB, 256, 0, stream>>>(xout, mlp_ln_g + l * SS, mlp_ln_b + l * SS, ubf);
    k_gemm_mfma<<<dim3(EE / 64, KS1), 256, 0, stream>>>(ubf, W1 + (size_t)l * EE * SS,
                                                        part, SS, EE);
    k_reduce1<<<EE / 8, 256, 0, stream>>>(part, b1 + (size_t)l * EE, hbf);
    k_gemm_mfma<<<dim3(SS / 64, KS2), 256, 0, stream>>>(hbf, W2 + (size_t)l * SS * EE,
                                                        part, EE, SS);
    k_reduce2<<<SS / 8, 256, 0, stream>>>(part, b2 + (size_t)l * SS, xout);
  }

  k_final<<<BB, 256, 0, stream>>>(xA, stats, (float*)d_out);
}